// Round 2
// baseline (328.733 us; speedup 1.0000x reference)
//
#include <hip/hip_runtime.h>

// SpatialLoss: x [64,16,256,256] f32 -> scalar
// loss = sum_{(i,j) in [-2,2]^2 \ (0,0)} (1/sqrt(i^2+j^2)) * sum((shifted diff)^2) / 64 / 256 / 256
// Symmetry (i,j) <-> (-i,-j): compute 12 half-space offsets with coeff 2/w.
// R2: 4-buffer register rotation (prefetch next row BEFORE accum, zero shift movs),
//     __launch_bounds__(256,4) to guarantee 4 blocks/CU -> whole grid co-resident.

#define RR 256
#define CCOLS 256
#define NPLANES 1024   // 64*16

__device__ __forceinline__ void load_row(const float* __restrict__ rowp, int sc, float (&W)[20]) {
    // window covers cols c0-2 .. c0+17 (clamped at plane edges; clamped values are masked out)
    const int c0 = sc << 4;
    const int lo = (sc == 0) ? 0 : (c0 - 2);
    const int hi = (sc == 15) ? (CCOLS - 2) : (c0 + 16);
    float2 l2 = *reinterpret_cast<const float2*>(rowp + lo);
    float4 q0 = *reinterpret_cast<const float4*>(rowp + c0);
    float4 q1 = *reinterpret_cast<const float4*>(rowp + c0 + 4);
    float4 q2 = *reinterpret_cast<const float4*>(rowp + c0 + 8);
    float4 q3 = *reinterpret_cast<const float4*>(rowp + c0 + 12);
    float2 h2 = *reinterpret_cast<const float2*>(rowp + hi);
    W[0]=l2.x;  W[1]=l2.y;
    W[2]=q0.x;  W[3]=q0.y;  W[4]=q0.z;  W[5]=q0.w;
    W[6]=q1.x;  W[7]=q1.y;  W[8]=q1.z;  W[9]=q1.w;
    W[10]=q2.x; W[11]=q2.y; W[12]=q2.z; W[13]=q2.w;
    W[14]=q3.x; W[15]=q3.y; W[16]=q3.z; W[17]=q3.w;
    W[18]=h2.x; W[19]=h2.y;
}

// A = row r, B = row r+1, C = row r+2. Center value for element k is A[k+2].
// Neighbor (k, j) lives at W[k+2+j]. Col masks: k+j<0 -> mL, k+j>15 -> mR (static per (k,j)).
template<bool EDGE>
__device__ __forceinline__ void accum(const float (&A)[20], const float (&B)[20], const float (&C)[20],
                                      float mL, float mR, float mB, float mC,
                                      float &a1, float &a2, float &a4, float &a5, float &a8)
{
#pragma unroll
    for (int k = 0; k < 16; ++k) {
        const float v = A[k + 2];
        // row A (i=0): j=1 (w=1), j=2 (w=2)
        {
            float d1 = A[k + 3] - v; if (k == 15) d1 *= mR;
            float d2 = A[k + 4] - v; if (k >= 14) d2 *= mR;
            a1 = fmaf(d1, d1, a1);
            a4 = fmaf(d2, d2, a4);
        }
        // row B (i=1): j=0 (w=1), j=+-1 (w=sqrt2), j=+-2 (w=sqrt5)
        {
            float d0  = B[k + 2] - v;
            float dm1 = B[k + 1] - v; if (k == 0)  dm1 *= mL;
            float dp1 = B[k + 3] - v; if (k == 15) dp1 *= mR;
            float dm2 = B[k + 0] - v; if (k <= 1)  dm2 *= mL;
            float dp2 = B[k + 4] - v; if (k >= 14) dp2 *= mR;
            if (EDGE) { d0 *= mB; dm1 *= mB; dp1 *= mB; dm2 *= mB; dp2 *= mB; }
            a1 = fmaf(d0,  d0,  a1);
            a2 = fmaf(dm1, dm1, a2);
            a2 = fmaf(dp1, dp1, a2);
            a5 = fmaf(dm2, dm2, a5);
            a5 = fmaf(dp2, dp2, a5);
        }
        // row C (i=2): j=0 (w=2), j=+-1 (w=sqrt5), j=+-2 (w=sqrt8)
        {
            float d0  = C[k + 2] - v;
            float dm1 = C[k + 1] - v; if (k == 0)  dm1 *= mL;
            float dp1 = C[k + 3] - v; if (k == 15) dp1 *= mR;
            float dm2 = C[k + 0] - v; if (k <= 1)  dm2 *= mL;
            float dp2 = C[k + 4] - v; if (k >= 14) dp2 *= mR;
            if (EDGE) { d0 *= mC; dm1 *= mC; dp1 *= mC; dm2 *= mC; dp2 *= mC; }
            a4 = fmaf(d0,  d0,  a4);
            a5 = fmaf(dm1, dm1, a5);
            a5 = fmaf(dp1, dp1, a5);
            a8 = fmaf(dm2, dm2, a8);
            a8 = fmaf(dp2, dp2, a8);
        }
    }
}

__global__ __launch_bounds__(256, 4) void spatial_loss_partial(const float* __restrict__ x,
                                                               float* __restrict__ partial)
{
    const int p   = blockIdx.x;           // plane 0..1023
    const int tid = threadIdx.x;
    const int sr  = tid >> 4;             // strip row 0..15 (16 rows each)
    const int sc  = tid & 15;             // strip col 0..15 (16 cols each)
    const float* plane = x + (size_t)p * (RR * CCOLS);
    const int r0 = sr << 4;

    float W0[20], W1[20], W2[20], W3[20];
    load_row(plane + (size_t)(r0    ) * CCOLS, sc, W0);
    load_row(plane + (size_t)(r0 + 1) * CCOLS, sc, W1);
    load_row(plane + (size_t)(r0 + 2) * CCOLS, sc, W2);

    const float mL = (sc == 0)  ? 0.f : 1.f;
    const float mR = (sc == 15) ? 0.f : 1.f;

    float a1 = 0.f, a2 = 0.f, a4 = 0.f, a5 = 0.f, a8 = 0.f;

    // i = 0..11: interior rows, 4-buffer rotation; prefetch row r0+i+3 into the
    // just-freed buffer BEFORE the accum so 384 VALU ops cover the load latency.
    // Rows prefetched here: r0+3 .. r0+14 (max 254) -> never clamped.
    const float* pn = plane + (size_t)(r0 + 3) * CCOLS;
#pragma unroll 1
    for (int g = 0; g < 3; ++g) {
        load_row(pn,             sc, W3); accum<false>(W0, W1, W2, mL, mR, 1.f, 1.f, a1, a2, a4, a5, a8);
        load_row(pn +     CCOLS, sc, W0); accum<false>(W1, W2, W3, mL, mR, 1.f, 1.f, a1, a2, a4, a5, a8);
        load_row(pn + 2 * CCOLS, sc, W1); accum<false>(W2, W3, W0, mL, mR, 1.f, 1.f, a1, a2, a4, a5, a8);
        load_row(pn + 3 * CCOLS, sc, W2); accum<false>(W3, W0, W1, mL, mR, 1.f, 1.f, a1, a2, a4, a5, a8);
        pn += 4 * CCOLS;
    }

    // tail i = 12..15 (pn == row r0+15, always <= 255). Bottom edge only for sr==15:
    // i=14: C = row r0+16 masked; i=15: B = r0+16, C = r0+17 masked.
    const float me  = (sr == 15) ? 0.f : 1.f;
    const int  r16  = (r0 + 16 > RR - 1) ? (RR - 1) : (r0 + 16);   // clamped rows are masked
    const int  r17  = (r0 + 17 > RR - 1) ? (RR - 1) : (r0 + 17);
    load_row(pn, sc, W3);
    accum<false>(W0, W1, W2, mL, mR, 1.f, 1.f, a1, a2, a4, a5, a8);                 // i=12
    load_row(plane + (size_t)r16 * CCOLS, sc, W0);
    accum<false>(W1, W2, W3, mL, mR, 1.f, 1.f, a1, a2, a4, a5, a8);                 // i=13
    load_row(plane + (size_t)r17 * CCOLS, sc, W1);
    accum<true >(W2, W3, W0, mL, mR, 1.f, me,  a1, a2, a4, a5, a8);                 // i=14
    accum<true >(W3, W0, W1, mL, mR, me,  me,  a1, a2, a4, a5, a8);                 // i=15

    // coefficients 2/w per weight class
    float loss = 2.0f * a1
               + 1.41421356237309515f  * a2     // 2/sqrt(2)
               + 1.0f                  * a4     // 2/2
               + 0.894427190999915878f * a5     // 2/sqrt(5)
               + 0.707106781186547573f * a8;    // 2/sqrt(8)

    // wave (64) reduce, then block reduce
    #pragma unroll
    for (int off = 32; off; off >>= 1) loss += __shfl_down(loss, off, 64);
    __shared__ float wsum[4];
    const int wave = tid >> 6, lane = tid & 63;
    if (lane == 0) wsum[wave] = loss;
    __syncthreads();
    if (tid == 0) partial[p] = wsum[0] + wsum[1] + wsum[2] + wsum[3];
}

__global__ __launch_bounds__(256) void reduce_partials(const float* __restrict__ partial,
                                                       float* __restrict__ out)
{
    const int tid = threadIdx.x;
    float s = partial[tid] + partial[tid + 256] + partial[tid + 512] + partial[tid + 768];
    #pragma unroll
    for (int off = 32; off; off >>= 1) s += __shfl_down(s, off, 64);
    __shared__ float wsum[4];
    if ((tid & 63) == 0) wsum[tid >> 6] = s;
    __syncthreads();
    if (tid == 0) out[0] = (wsum[0] + wsum[1] + wsum[2] + wsum[3]) * (1.0f / 4194304.0f);
}

extern "C" void kernel_launch(void* const* d_in, const int* in_sizes, int n_in,
                              void* d_out, int out_size, void* d_ws, size_t ws_size,
                              hipStream_t stream) {
    const float* x = (const float*)d_in[0];
    float* out     = (float*)d_out;
    float* partial = (float*)d_ws;   // 1024 floats = 4 KB
    spatial_loss_partial<<<NPLANES, 256, 0, stream>>>(x, partial);
    reduce_partials<<<1, 256, 0, stream>>>(partial, out);
}

// Round 3
// 64.768 us; speedup vs baseline: 5.0755x; 5.0755x over previous
//
#include <hip/hip_runtime.h>

// SpatialLoss: x [64,16,256,256] f32 -> scalar
// loss = sum_{(i,j) in [-2,2]^2 \ (0,0)} (1/sqrt(i^2+j^2)) * sum((shifted diff)^2) / 64 / 256 / 256
// Symmetry (i,j) <-> (-i,-j): compute 12 half-space offsets with coeff 2/w.
// R3: narrow 4-col strips -> 4x8-float rotation buffers (32 VGPR of window) so the
//     live set fits under the 64-VGPR occupancy step WITHOUT a launch-bounds clamp
//     (R2's clamp caused wholesale scratch demotion: 486 MB of spill writes).
//     Grid 2048 (half-plane blocks), one wave = one full row -> coalesced 1KB loads.

#define RR 256
#define CCOLS 256

__device__ __forceinline__ void load_row8(const float* __restrict__ rowp, int sc, float (&W)[8]) {
    // window covers cols c0-2 .. c0+5 (clamped at plane edges; clamped values are masked out)
    const int c0 = sc << 2;
    const int lo = (sc == 0)  ? 0 : (c0 - 2);
    const int hi = (sc == 63) ? (CCOLS - 2) : (c0 + 4);
    float2 l2 = *reinterpret_cast<const float2*>(rowp + lo);
    float4 q  = *reinterpret_cast<const float4*>(rowp + c0);
    float2 h2 = *reinterpret_cast<const float2*>(rowp + hi);
    W[0]=l2.x; W[1]=l2.y; W[2]=q.x; W[3]=q.y; W[4]=q.z; W[5]=q.w; W[6]=h2.x; W[7]=h2.y;
}

// A = row r, B = row r+1, C = row r+2. Center element k (0..3) is A[k+2];
// neighbor (k,j) is W[k+2+j]. Col masks static per (k,j): mL left edge, mR right edge.
template<bool EDGE>
__device__ __forceinline__ void accum4(const float (&A)[8], const float (&B)[8], const float (&C)[8],
                                       float mL, float mR, float mB, float mC,
                                       float &a1, float &a2, float &a4, float &a5, float &a8)
{
#pragma unroll
    for (int k = 0; k < 4; ++k) {
        const float v = A[k + 2];
        // row A (i=0): j=1 (w=1), j=2 (w=2)
        {
            float d1 = A[k + 3] - v; if (k == 3) d1 *= mR;
            float d2 = A[k + 4] - v; if (k >= 2) d2 *= mR;
            a1 = fmaf(d1, d1, a1);
            a4 = fmaf(d2, d2, a4);
        }
        // row B (i=1): j=0 (w=1), j=+-1 (w=sqrt2), j=+-2 (w=sqrt5)
        {
            float d0  = B[k + 2] - v;
            float dm1 = B[k + 1] - v; if (k == 0) dm1 *= mL;
            float dp1 = B[k + 3] - v; if (k == 3) dp1 *= mR;
            float dm2 = B[k + 0] - v; if (k <= 1) dm2 *= mL;
            float dp2 = B[k + 4] - v; if (k >= 2) dp2 *= mR;
            if (EDGE) { d0 *= mB; dm1 *= mB; dp1 *= mB; dm2 *= mB; dp2 *= mB; }
            a1 = fmaf(d0,  d0,  a1);
            a2 = fmaf(dm1, dm1, a2);
            a2 = fmaf(dp1, dp1, a2);
            a5 = fmaf(dm2, dm2, a5);
            a5 = fmaf(dp2, dp2, a5);
        }
        // row C (i=2): j=0 (w=2), j=+-1 (w=sqrt5), j=+-2 (w=sqrt8)
        {
            float d0  = C[k + 2] - v;
            float dm1 = C[k + 1] - v; if (k == 0) dm1 *= mL;
            float dp1 = C[k + 3] - v; if (k == 3) dp1 *= mR;
            float dm2 = C[k + 0] - v; if (k <= 1) dm2 *= mL;
            float dp2 = C[k + 4] - v; if (k >= 2) dp2 *= mR;
            if (EDGE) { d0 *= mC; dm1 *= mC; dp1 *= mC; dm2 *= mC; dp2 *= mC; }
            a4 = fmaf(d0,  d0,  a4);
            a5 = fmaf(dm1, dm1, a5);
            a5 = fmaf(dp1, dp1, a5);
            a8 = fmaf(dm2, dm2, a8);
            a8 = fmaf(dp2, dp2, a8);
        }
    }
}

__global__ __launch_bounds__(256) void spatial_loss_partial(const float* __restrict__ x,
                                                            float* __restrict__ partial)
{
    const int b   = blockIdx.x;          // 0..2047: plane b>>1, half b&1
    const int tid = threadIdx.x;
    const int sr  = tid >> 6;            // 0..3   (one wave per sr: 64 lanes = full row)
    const int sc  = tid & 63;            // 0..63  (4 cols each)
    const float* plane = x + (size_t)(b >> 1) * (RR * CCOLS);
    const int r0 = ((b & 1) << 7) + (sr << 5);   // 0,32,...,224

    float W0[8], W1[8], W2[8], W3[8];
    load_row8(plane + (size_t)(r0    ) * CCOLS, sc, W0);
    load_row8(plane + (size_t)(r0 + 1) * CCOLS, sc, W1);
    load_row8(plane + (size_t)(r0 + 2) * CCOLS, sc, W2);

    const float mL = (sc == 0)  ? 0.f : 1.f;
    const float mR = (sc == 63) ? 0.f : 1.f;

    float a1 = 0.f, a2 = 0.f, a4 = 0.f, a5 = 0.f, a8 = 0.f;

    // i = 0..27: 7 groups of 4, cyclic buffers; prefetch row r0+i+3 into the freed
    // buffer BEFORE the accum so the ~111 VALU ops cover the load latency.
    // Prefetched rows r0+3 .. r0+30 (max abs 254) -> never clamped.
    const float* pn = plane + (size_t)(r0 + 3) * CCOLS;
#pragma unroll 1
    for (int g = 0; g < 7; ++g) {
        load_row8(pn,             sc, W3); accum4<false>(W0, W1, W2, mL, mR, 1.f, 1.f, a1, a2, a4, a5, a8);
        load_row8(pn +     CCOLS, sc, W0); accum4<false>(W1, W2, W3, mL, mR, 1.f, 1.f, a1, a2, a4, a5, a8);
        load_row8(pn + 2 * CCOLS, sc, W1); accum4<false>(W2, W3, W0, mL, mR, 1.f, 1.f, a1, a2, a4, a5, a8);
        load_row8(pn + 3 * CCOLS, sc, W2); accum4<false>(W3, W0, W1, mL, mR, 1.f, 1.f, a1, a2, a4, a5, a8);
        pn += 4 * CCOLS;
    }

    // tail i = 28..31; buffers now hold rows (r0+28, r0+29, r0+30).
    // Bottom edge only for the absolute-last strip (r0 == 224).
    const float me  = (r0 == 224) ? 0.f : 1.f;
    const int  r32  = (r0 + 32 > RR - 1) ? (RR - 1) : (r0 + 32);   // clamped rows are masked
    const int  r33  = (r0 + 33 > RR - 1) ? (RR - 1) : (r0 + 33);
    load_row8(pn, sc, W3);                                         // row r0+31 (<=255 always)
    accum4<false>(W0, W1, W2, mL, mR, 1.f, 1.f, a1, a2, a4, a5, a8);              // i=28
    load_row8(plane + (size_t)r32 * CCOLS, sc, W0);
    accum4<false>(W1, W2, W3, mL, mR, 1.f, 1.f, a1, a2, a4, a5, a8);              // i=29
    load_row8(plane + (size_t)r33 * CCOLS, sc, W1);
    accum4<true >(W2, W3, W0, mL, mR, 1.f, me,  a1, a2, a4, a5, a8);              // i=30
    accum4<true >(W3, W0, W1, mL, mR, me,  me,  a1, a2, a4, a5, a8);              // i=31

    // coefficients 2/w per weight class
    float loss = 2.0f * a1
               + 1.41421356237309515f  * a2     // 2/sqrt(2)
               + 1.0f                  * a4     // 2/2
               + 0.894427190999915878f * a5     // 2/sqrt(5)
               + 0.707106781186547573f * a8;    // 2/sqrt(8)

    // wave (64) reduce, then block reduce
    #pragma unroll
    for (int off = 32; off; off >>= 1) loss += __shfl_down(loss, off, 64);
    __shared__ float wsum[4];
    const int wave = tid >> 6, lane = tid & 63;
    if (lane == 0) wsum[wave] = loss;
    __syncthreads();
    if (tid == 0) partial[b] = wsum[0] + wsum[1] + wsum[2] + wsum[3];
}

__global__ __launch_bounds__(256) void reduce_partials(const float* __restrict__ partial,
                                                       float* __restrict__ out)
{
    const int tid = threadIdx.x;
    float s = 0.f;
    #pragma unroll
    for (int q = 0; q < 8; ++q) s += partial[tid + (q << 8)];
    #pragma unroll
    for (int off = 32; off; off >>= 1) s += __shfl_down(s, off, 64);
    __shared__ float wsum[4];
    if ((tid & 63) == 0) wsum[tid >> 6] = s;
    __syncthreads();
    if (tid == 0) out[0] = (wsum[0] + wsum[1] + wsum[2] + wsum[3]) * (1.0f / 4194304.0f);
}

extern "C" void kernel_launch(void* const* d_in, const int* in_sizes, int n_in,
                              void* d_out, int out_size, void* d_ws, size_t ws_size,
                              hipStream_t stream) {
    const float* x = (const float*)d_in[0];
    float* out     = (float*)d_out;
    float* partial = (float*)d_ws;   // 2048 floats = 8 KB
    spatial_loss_partial<<<2048, 256, 0, stream>>>(x, partial);
    reduce_partials<<<1, 256, 0, stream>>>(partial, out);
}

// Round 4
// 49.663 us; speedup vs baseline: 6.6192x; 1.3041x over previous
//
#include <hip/hip_runtime.h>

// SpatialLoss: x [64,16,256,256] f32 -> scalar
// loss = sum_{(i,j) in [-2,2]^2 \ (0,0)} (1/sqrt(i^2+j^2)) * sum((shifted diff)^2) / 64 / 256 / 256
//
// R4: product form. For each ordered offset d: sum (x[p+d]-x[p])^2 =
//     sum W(q) x[q]^2 (q over all pixels, W = sum of 1/w over q's in-bounds
//     24-neighborhood) - 4 * sum_{half-space d} (1/w) sum_p x[p]*x[p+d].
//     Cross terms use ZERO-PADDED windows -> no edge masks at all.
//     Interior body: 13 VALU/element (vs 26 in diff form), short FMA chains.
//     Row-border weight corrections (rows 0,1,254,255) applied outside hot loop.

#define RR 256
#define CCOLS 256

// g(j) = sum_{i=-2..2,(i,j)!=(0,0)} 1/sqrt(i*i+j*j)
#define G1 3.30864075337301081f   // j=+-1
#define G2 2.10153397218646371f   // j=+-2
// m_r(j): missing 1/w weight for border rows. row0/row255: i in {-1,-2} missing.
#define M00 1.5f                  // j=0
#define M01 1.15432037668650540f  // 1/sqrt(2)+1/sqrt(5)
#define M02 0.80076698609323170f  // 1/sqrt(5)+1/sqrt(8)
// row1/row254: i=-2 missing.
#define M10 0.5f
#define M11 0.44721359549995794f  // 1/sqrt(5)
#define M12 0.35355339059327376f  // 1/sqrt(8)

#define RS2 0.70710678118654752f  // 1/sqrt(2)
#define RS5 0.44721359549995794f  // 1/sqrt(5)
#define RS8 0.35355339059327376f  // 1/sqrt(8)

// Load 8-float window (cols 4*sc-2 .. 4*sc+5) with ZERO padding at plane edges.
// Addresses stay in-bounds (clamped); padded slots forced to 0 via cndmask.
__device__ __forceinline__ void load_row8z(const float* __restrict__ rowp, int sc, float (&W)[8]) {
    const int c0 = sc << 2;
    const int lo = (sc == 0)  ? 0 : (c0 - 2);
    const int hi = (sc == 63) ? (CCOLS - 2) : (c0 + 4);
    float2 l2 = *reinterpret_cast<const float2*>(rowp + lo);
    float4 q  = *reinterpret_cast<const float4*>(rowp + c0);
    float2 h2 = *reinterpret_cast<const float2*>(rowp + hi);
    const bool e0 = (sc == 0), e1 = (sc == 63);
    W[0] = e0 ? 0.f : l2.x;  W[1] = e0 ? 0.f : l2.y;
    W[2] = q.x; W[3] = q.y; W[4] = q.z; W[5] = q.w;
    W[6] = e1 ? 0.f : h2.x;  W[7] = e1 ? 0.f : h2.y;
}

// A=row r, B=row r+1, C=row r+2; center element k is A[k+2], neighbor (k,j)=W[k+2+j].
// Half-space offsets: w=1:(0,1),(1,0); w=sqrt2:(1,+-1); w=2:(0,2),(2,0);
// w=sqrt5:(1,+-2),(2,+-1); w=sqrt8:(2,+-2). Zero-padding makes invalid products 0.
__device__ __forceinline__ void pacc4(const float (&A)[8], const float (&B)[8], const float (&C)[8],
                                      float &s1, float &s2, float &s4, float &s5, float &s8,
                                      float (&Q)[4])
{
#pragma unroll
    for (int k = 0; k < 4; ++k) {
        const float v = A[k + 2];
        Q[k] = fmaf(v, v, Q[k]);
        s1 = fmaf(v, A[k + 3] + B[k + 2], s1);
        s2 = fmaf(v, B[k + 1] + B[k + 3], s2);
        s4 = fmaf(v, A[k + 4] + C[k + 2], s4);
        s5 = fmaf(v, (B[k] + B[k + 4]) + (C[k + 1] + C[k + 3]), s5);
        s8 = fmaf(v, C[k] + C[k + 4], s8);
    }
}

__global__ __launch_bounds__(256) void spatial_loss_partial(const float* __restrict__ x,
                                                            float* __restrict__ partial)
{
    const int b   = blockIdx.x;          // 0..2047: plane b>>1, half b&1
    const int tid = threadIdx.x;
    const int sr  = tid >> 6;            // wave id: one wave = one full 256-col row
    const int sc  = tid & 63;            // 4 cols per lane
    const float* plane = x + (size_t)(b >> 1) * (RR * CCOLS);
    const int r0 = ((b & 1) << 7) + (sr << 5);   // 0,32,...,224
    const int cbase = sc << 2;

    float W0[8], W1[8], W2[8], W3[8];
    load_row8z(plane + (size_t)(r0    ) * CCOLS, sc, W0);
    load_row8z(plane + (size_t)(r0 + 1) * CCOLS, sc, W1);
    load_row8z(plane + (size_t)(r0 + 2) * CCOLS, sc, W2);

    // per-lane interior-row squared-term weights W(c) = g0 + a*g1 + b*g2
    float Wk[4];
#pragma unroll
    for (int k = 0; k < 4; ++k) {
        const int c  = cbase + k;
        const float a = ((c >= 1) ? 1.f : 0.f) + ((c <= 254) ? 1.f : 0.f);
        const float bb = ((c >= 2) ? 1.f : 0.f) + ((c <= 253) ? 1.f : 0.f);
        Wk[k] = 3.0f + a * G1 + bb * G2;
    }

    float s1 = 0.f, s2 = 0.f, s4 = 0.f, s5 = 0.f, s8 = 0.f;
    float Q[4] = {0.f, 0.f, 0.f, 0.f};
    float bacc = 0.f;   // border-row weight corrections (to subtract)

    if (r0 == 0) {      // rows 0 and 1: centers currently in W0, W1
#pragma unroll
        for (int k = 0; k < 4; ++k) {
            const int c  = cbase + k;
            const float a = ((c >= 1) ? 1.f : 0.f) + ((c <= 254) ? 1.f : 0.f);
            const float bb = ((c >= 2) ? 1.f : 0.f) + ((c <= 253) ? 1.f : 0.f);
            const float cw0 = M00 + a * M01 + bb * M02;
            const float cw1 = M10 + a * M11 + bb * M12;
            const float v0 = W0[k + 2], v1 = W1[k + 2];
            bacc = fmaf(cw0, v0 * v0, bacc);
            bacc = fmaf(cw1, v1 * v1, bacc);
        }
    }

    // i = 0..27: rotation; prefetch row r0+i+3 (rows r0+3..r0+30, always <= 254).
    const float* pn = plane + (size_t)(r0 + 3) * CCOLS;
#pragma unroll 1
    for (int g = 0; g < 7; ++g) {
        load_row8z(pn,             sc, W3); pacc4(W0, W1, W2, s1, s2, s4, s5, s8, Q);
        load_row8z(pn +     CCOLS, sc, W0); pacc4(W1, W2, W3, s1, s2, s4, s5, s8, Q);
        load_row8z(pn + 2 * CCOLS, sc, W1); pacc4(W2, W3, W0, s1, s2, s4, s5, s8, Q);
        load_row8z(pn + 3 * CCOLS, sc, W2); pacc4(W3, W0, W1, s1, s2, s4, s5, s8, Q);
        pn += 4 * CCOLS;
    }

    // tail i = 28..31. Rows r0+32, r0+33 are zero-padded for the last strip.
    const bool last = (r0 == 224);
    load_row8z(pn, sc, W3);                                   // row r0+31 (<=255)
    pacc4(W0, W1, W2, s1, s2, s4, s5, s8, Q);                 // i=28
    if (last) {
#pragma unroll
        for (int q = 0; q < 8; ++q) W0[q] = 0.f;
    } else {
        load_row8z(plane + (size_t)(r0 + 32) * CCOLS, sc, W0);
    }
    pacc4(W1, W2, W3, s1, s2, s4, s5, s8, Q);                 // i=29
    if (last) {
#pragma unroll
        for (int q = 0; q < 8; ++q) W1[q] = 0.f;
    } else {
        load_row8z(plane + (size_t)(r0 + 33) * CCOLS, sc, W1);
    }
    pacc4(W2, W3, W0, s1, s2, s4, s5, s8, Q);                 // i=30 (row r0+30)
    pacc4(W3, W0, W1, s1, s2, s4, s5, s8, Q);                 // i=31 (row r0+31)

    if (last) {         // rows 254 (W2 centers) and 255 (W3 centers) corrections
#pragma unroll
        for (int k = 0; k < 4; ++k) {
            const int c  = cbase + k;
            const float a = ((c >= 1) ? 1.f : 0.f) + ((c <= 254) ? 1.f : 0.f);
            const float bb = ((c >= 2) ? 1.f : 0.f) + ((c <= 253) ? 1.f : 0.f);
            const float cw254 = M10 + a * M11 + bb * M12;     // like row 1
            const float cw255 = M00 + a * M01 + bb * M02;     // like row 0
            const float v4 = W2[k + 2], v5 = W3[k + 2];
            bacc = fmaf(cw254, v4 * v4, bacc);
            bacc = fmaf(cw255, v5 * v5, bacc);
        }
    }

    const float sq = fmaf(Wk[0], Q[0], fmaf(Wk[1], Q[1], fmaf(Wk[2], Q[2], Wk[3] * Q[3]))) - bacc;
    const float cross = s1 + RS2 * s2 + 0.5f * s4 + RS5 * s5 + RS8 * s8;
    float t = 2.0f * sq - 4.0f * cross;

    // wave (64) reduce, then block reduce
    #pragma unroll
    for (int off = 32; off; off >>= 1) t += __shfl_down(t, off, 64);
    __shared__ float wsum[4];
    const int wave = tid >> 6, lane = tid & 63;
    if (lane == 0) wsum[wave] = t;
    __syncthreads();
    if (tid == 0) partial[b] = wsum[0] + wsum[1] + wsum[2] + wsum[3];
}

__global__ __launch_bounds__(256) void reduce_partials(const float* __restrict__ partial,
                                                       float* __restrict__ out)
{
    const int tid = threadIdx.x;
    float s = 0.f;
    #pragma unroll
    for (int q = 0; q < 8; ++q) s += partial[tid + (q << 8)];
    #pragma unroll
    for (int off = 32; off; off >>= 1) s += __shfl_down(s, off, 64);
    __shared__ float wsum[4];
    if ((tid & 63) == 0) wsum[tid >> 6] = s;
    __syncthreads();
    if (tid == 0) out[0] = (wsum[0] + wsum[1] + wsum[2] + wsum[3]) * (1.0f / 4194304.0f);
}

extern "C" void kernel_launch(void* const* d_in, const int* in_sizes, int n_in,
                              void* d_out, int out_size, void* d_ws, size_t ws_size,
                              hipStream_t stream) {
    const float* x = (const float*)d_in[0];
    float* out     = (float*)d_out;
    float* partial = (float*)d_ws;   // 2048 floats = 8 KB
    spatial_loss_partial<<<2048, 256, 0, stream>>>(x, partial);
    reduce_partials<<<1, 256, 0, stream>>>(partial, out);
}